// Round 7
// baseline (1482.749 us; speedup 1.0000x reference)
//
#include <hip/hip_runtime.h>
#include <hip/hip_bf16.h>
#include <math.h>

#define BGR   8192        // graphs
#define NND   9           // nodes per graph
#define BN    73728       // BGR*NND
#define NE    131072      // BGR*16 explicit edges
#define ETOT  204800      // NE + BN (self loops)
#define H     128
#define MH    256
#define FIN   15

typedef __bf16 bf16_t;
typedef bf16_t bf16x8 __attribute__((ext_vector_type(8)));
typedef float  f32x4  __attribute__((ext_vector_type(4)));

__device__ __forceinline__ unsigned short f2bf(float f) {
    unsigned int u = __float_as_uint(f);
    u += 0x7fff + ((u >> 16) & 1);           // RNE (inputs are finite)
    return (unsigned short)(u >> 16);
}
__device__ __forceinline__ unsigned int pkbf(float a, float b) {
    union { __hip_bfloat162 h; unsigned int u; } un;
    un.h = __float22bfloat162_rn(make_float2(a, b));
    return un.u;
}
__device__ __forceinline__ bf16x8 as_frag(int4 v) {
    union { int4 i; bf16x8 f; } u; u.i = v; return u.f;
}
__device__ __forceinline__ float fast_tanh(float v) {
    float e = __expf(2.0f * v);
    return 1.0f - __fdividef(2.0f, e + 1.0f);
}
// swizzled LDS offset (elements) for element (m, k) in a 64 x 256 bf16 tile
__device__ __forceinline__ int sw_off(int m, int k) {
    return m * 256 + ((((k >> 3) ^ (m & 7)) << 3) | (k & 7));
}

// ---------------------------------------------------------------- deg kernel
__global__ void deg_kernel(const int* __restrict__ edges, float* __restrict__ inv_deg) {
    int g = blockIdx.x * 256 + threadIdx.x;
    if (g >= BGR) return;
    int cnt[NND];
#pragma unroll
    for (int n = 0; n < NND; ++n) cnt[n] = 1;   // self loop
    for (int j = 0; j < 16; ++j) {
        int d = edges[g * 32 + 16 + j];
#pragma unroll
        for (int n = 0; n < NND; ++n) cnt[n] += (d == n) ? 1 : 0;
    }
#pragma unroll
    for (int n = 0; n < NND; ++n) inv_deg[g * NND + n] = 1.0f / (float)cnt[n];
}

// ---------------------------------------------------------------- encoder
__global__ void enc_kernel(const float* __restrict__ obs, const float* __restrict__ W,
                           const float* __restrict__ b, float* __restrict__ x) {
    int tid = blockIdx.x * 256 + threadIdx.x;     // BN*128 threads
    int i = tid >> 7, h = tid & 127;
    float acc = b[h];
#pragma unroll
    for (int k = 0; k < FIN; ++k) acc += obs[i * FIN + k] * W[k * H + h];
    x[i * H + h] = tanhf(acc);
}

// ---------------------------------------------------------------- weight transpose+bf16
// out: [W1T 4x256x256][W2T 4x256x256][W3T 4x128x256][WG 4x512x256][dW1T 256x128][dW2T 256x256]
// WG packed col p = w*64 + gate*16 + c  ->  (gate, h = w*16 + c), w=0..7
__global__ void wt_kernel(const float* __restrict__ W1, const float* __restrict__ W2,
                          const float* __restrict__ W3, const float* __restrict__ Wi,
                          const float* __restrict__ Wh, const float* __restrict__ dW1,
                          const float* __restrict__ dW2, unsigned short* __restrict__ out) {
    int idx = blockIdx.x * 256 + threadIdx.x;     // 1277952 total
    float v;
    if (idx < 262144) {
        int s = idx >> 16, r = idx & 65535, n = r >> 8, k = r & 255;
        v = W1[(s << 16) + (k << 8) + n];
    } else if (idx < 524288) {
        int i2 = idx - 262144;
        int s = i2 >> 16, r = i2 & 65535, n = r >> 8, k = r & 255;
        v = W2[(s << 16) + (k << 8) + n];
    } else if (idx < 655360) {
        int i3 = idx - 524288;
        int s = i3 >> 15, r = i3 & 32767, n = r >> 8, k = r & 255;
        v = W3[(s << 15) + (k << 7) + n];
    } else if (idx < 1179648) {
        int i4 = idx - 655360;                    // 0..524287
        int s = i4 >> 17, rr = i4 & 131071;
        int p = rr >> 8, k = rr & 255;
        int w = p >> 6, rem = p & 63;
        int gate = rem >> 4, c = rem & 15;
        int h = w * 16 + c;
        const int sb = s * 49152;                 // 128*384
        if (gate == 0)      v = (k < 128) ? Wi[sb + k * 384 + h]       : Wh[sb + (k - 128) * 384 + h];
        else if (gate == 1) v = (k < 128) ? Wi[sb + k * 384 + 128 + h] : Wh[sb + (k - 128) * 384 + 128 + h];
        else if (gate == 2) v = (k < 128) ? Wi[sb + k * 384 + 256 + h] : 0.f;
        else                v = (k < 128) ? 0.f                        : Wh[sb + (k - 128) * 384 + 256 + h];
    } else if (idx < 1212416) {
        int i5 = idx - 1179648;                   // dW1T [256][128]
        int n = i5 >> 7, k = i5 & 127;
        v = dW1[k * 256 + n];
    } else {
        int i6 = idx - 1212416;                   // dW2T [256][256]
        int n = i6 >> 8, k = i6 & 255;
        v = dW2[k * 256 + n];
    }
    out[idx] = f2bf(v);
}

// ---------------------------------------------------------------- fused msg MLP, MFMA bf16
// 64 edges / block, 512 threads (8 waves). Wave w owns n-slice w*32 (layers 1-2),
// n-slice w*16 (layer 3). Single 32 KB LDS buffer.
// __launch_bounds__(512,8): 8 waves/EU -> 4 blocks/CU (32 waves = HW max), VGPR cap 64
// (kernel measured 52 at the 128 cap -> fits; watch FETCH_SIZE for spill regression).
__global__ __launch_bounds__(512, 8) void msg_mfma(
        const float* __restrict__ x, const int* __restrict__ edges,
        const unsigned short* __restrict__ W1T, const float* __restrict__ b1,
        const unsigned short* __restrict__ W2T, const float* __restrict__ b2,
        const unsigned short* __restrict__ W3T,
        float* __restrict__ aggr) {
    __shared__ unsigned short buf[64 * 256];   // 32 KB, swizzled [m][k]
    __shared__ int sdst[64];
    const int t  = threadIdx.x;
    const int e0 = blockIdx.x * 64;
    const int wv = t >> 6;        // 0..7
    const int ln = t & 63;
    const int lrow = ln & 15;
    const int lq   = ln >> 4;

    // ---- stage A0 = bf16(concat(x[dst], x[src])); also stage dst indices
    if (t < 64) {
        const int eg = e0 + t;
        sdst[t] = (eg < NE) ? ((eg >> 4) * NND + edges[(eg >> 4) * 32 + 16 + (eg & 15)])
                            : (eg - NE);
    }
    {
        const int row  = t >> 2;          // 0..127
        const int q    = t & 3;
        const int e    = row & 63;
        const int side = row >> 6;        // 0 -> dst cols 0..127, 1 -> src cols 128..255
        const int eg   = e0 + e;
        int node;
        if (eg < NE) {
            int g = eg >> 4, j = eg & 15;
            node = g * NND + (side ? edges[g * 32 + j] : edges[g * 32 + 16 + j]);
        } else {
            node = eg - NE;
        }
        const float* xs = x + (size_t)node * H + q * 32;
        const int kbase = side * 128 + q * 32;
#pragma unroll
        for (int i = 0; i < 8; ++i) {
            float4 v = *(const float4*)(xs + i * 4);
            uint2 o;
            o.x = pkbf(v.x, v.y); o.y = pkbf(v.z, v.w);
            *(uint2*)(buf + sw_off(e, kbase + i * 4)) = o;
        }
    }
    __syncthreads();

    const f32x4 zero = {0.f, 0.f, 0.f, 0.f};
    const int nbase = wv * 32;
    const unsigned short* w1p0 = W1T + (size_t)(nbase + lrow) * 256;
    const unsigned short* w1p1 = W1T + (size_t)(nbase + 16 + lrow) * 256;
    const unsigned short* w2p0 = W2T + (size_t)(nbase + lrow) * 256;
    const unsigned short* w2p1 = W2T + (size_t)(nbase + 16 + lrow) * 256;
    const unsigned short* w3p  = W3T + (size_t)(wv * 16 + lrow) * 256;

    // ---- layer 1
    {
        f32x4 acc[4][2];
#pragma unroll
        for (int i = 0; i < 4; ++i)
#pragma unroll
            for (int j = 0; j < 2; ++j) acc[i][j] = zero;
#pragma unroll
        for (int kq = 0; kq < 8; ++kq) {
            const int ko = kq * 32 + lq * 8;
            bf16x8 af[4], bfr[2];
#pragma unroll
            for (int tm = 0; tm < 4; ++tm)
                af[tm] = as_frag(*(const int4*)(buf + sw_off(tm * 16 + lrow, ko)));
            bfr[0] = as_frag(*(const int4*)(w1p0 + ko));
            bfr[1] = as_frag(*(const int4*)(w1p1 + ko));
#pragma unroll
            for (int tm = 0; tm < 4; ++tm)
#pragma unroll
                for (int tn = 0; tn < 2; ++tn)
                    acc[tm][tn] = __builtin_amdgcn_mfma_f32_16x16x32_bf16(af[tm], bfr[tn], acc[tm][tn], 0, 0, 0);
        }
        __syncthreads();                      // all reads of buf done
#pragma unroll
        for (int tn = 0; tn < 2; ++tn) {
            const int n = nbase + tn * 16 + lrow;
            const float bias = b1[n];
#pragma unroll
            for (int tm = 0; tm < 4; ++tm)
#pragma unroll
                for (int r = 0; r < 4; ++r) {
                    const int m = tm * 16 + lq * 4 + r;
                    buf[sw_off(m, n)] = f2bf(fast_tanh(acc[tm][tn][r] + bias));
                }
        }
    }
    __syncthreads();

    // ---- layer 2
    {
        f32x4 acc[4][2];
#pragma unroll
        for (int i = 0; i < 4; ++i)
#pragma unroll
            for (int j = 0; j < 2; ++j) acc[i][j] = zero;
#pragma unroll
        for (int kq = 0; kq < 8; ++kq) {
            const int ko = kq * 32 + lq * 8;
            bf16x8 af[4], bfr[2];
#pragma unroll
            for (int tm = 0; tm < 4; ++tm)
                af[tm] = as_frag(*(const int4*)(buf + sw_off(tm * 16 + lrow, ko)));
            bfr[0] = as_frag(*(const int4*)(w2p0 + ko));
            bfr[1] = as_frag(*(const int4*)(w2p1 + ko));
#pragma unroll
            for (int tm = 0; tm < 4; ++tm)
#pragma unroll
                for (int tn = 0; tn < 2; ++tn)
                    acc[tm][tn] = __builtin_amdgcn_mfma_f32_16x16x32_bf16(af[tm], bfr[tn], acc[tm][tn], 0, 0, 0);
        }
        __syncthreads();
#pragma unroll
        for (int tn = 0; tn < 2; ++tn) {
            const int n = nbase + tn * 16 + lrow;
            const float bias = b2[n];
#pragma unroll
            for (int tm = 0; tm < 4; ++tm)
#pragma unroll
                for (int r = 0; r < 4; ++r) {
                    const int m = tm * 16 + lq * 4 + r;
                    buf[sw_off(m, n)] = f2bf(fast_tanh(acc[tm][tn][r] + bias));
                }
        }
    }
    __syncthreads();

    // ---- layer 3: N=128, wave w -> n-slice w*16; atomic scatter (b3 deferred to GRU)
    {
        f32x4 acc3[4];
#pragma unroll
        for (int i = 0; i < 4; ++i) acc3[i] = zero;
#pragma unroll
        for (int kq = 0; kq < 8; ++kq) {
            const int ko = kq * 32 + lq * 8;
            bf16x8 af[4];
#pragma unroll
            for (int tm = 0; tm < 4; ++tm)
                af[tm] = as_frag(*(const int4*)(buf + sw_off(tm * 16 + lrow, ko)));
            const bf16x8 bfr = as_frag(*(const int4*)(w3p + ko));
#pragma unroll
            for (int tm = 0; tm < 4; ++tm)
                acc3[tm] = __builtin_amdgcn_mfma_f32_16x16x32_bf16(af[tm], bfr, acc3[tm], 0, 0, 0);
        }
        const int n = wv * 16 + lrow;
#pragma unroll
        for (int tm = 0; tm < 4; ++tm)
#pragma unroll
            for (int r = 0; r < 4; ++r) {
                const int m = tm * 16 + lq * 4 + r;
                atomicAdd(aggr + (size_t)sdst[m] * H + n, acc3[tm][r]);
            }
    }
}

// ---------------------------------------------------------------- GRU via MFMA (64 nodes / block, 512 thr)
// Wave w owns packed cols w*64..w*64+63 = all 4 gates of h-slice w*16..w*16+15.
__global__ __launch_bounds__(512, 4) void gru_mfma(
        float* __restrict__ x, float* __restrict__ aggr, const float* __restrict__ inv_deg,
        const unsigned short* __restrict__ WG, const float* __restrict__ b3m,
        const float* __restrict__ bi, const float* __restrict__ bh) {
    __shared__ unsigned short bufA[64 * 256];   // 32 KB
    const int t = threadIdx.x;
    const int n0 = blockIdx.x * 64;
    const int wv = t >> 6, ln = t & 63, lrow = ln & 15, lq = ln >> 4;

    // stage A = bf16([aggr*inv_deg + b3 | x]): m = t>>3, k-slice q*32
    {
        const int m = t >> 3;
        const int q = t & 7;
        const int k0 = q * 32;
        const int node = n0 + m;
        if (q < 4) {
            const float scale = inv_deg[node];
            const float* src = aggr + (size_t)node * H + k0;
#pragma unroll
            for (int i = 0; i < 8; ++i) {
                float4 v = *(const float4*)(src + i * 4);
                const float4 bb = *(const float4*)(b3m + k0 + i * 4);
                v.x = v.x * scale + bb.x; v.y = v.y * scale + bb.y;
                v.z = v.z * scale + bb.z; v.w = v.w * scale + bb.w;
                uint2 o; o.x = pkbf(v.x, v.y); o.y = pkbf(v.z, v.w);
                *(uint2*)(bufA + sw_off(m, k0 + i * 4)) = o;
            }
        } else {
            const float* src = x + (size_t)node * H + (k0 - 128);
#pragma unroll
            for (int i = 0; i < 8; ++i) {
                float4 v = *(const float4*)(src + i * 4);
                uint2 o; o.x = pkbf(v.x, v.y); o.y = pkbf(v.z, v.w);
                *(uint2*)(bufA + sw_off(m, k0 + i * 4)) = o;
            }
        }
    }
    __syncthreads();

    const f32x4 zero = {0.f, 0.f, 0.f, 0.f};
    f32x4 acc[4][4];    // [m-tile][gate]
#pragma unroll
    for (int i = 0; i < 4; ++i)
#pragma unroll
        for (int j = 0; j < 4; ++j) acc[i][j] = zero;

    const unsigned short* wgp = WG + (size_t)(wv * 64 + lrow) * 256;
#pragma unroll
    for (int kq = 0; kq < 8; ++kq) {
        const int ko = kq * 32 + lq * 8;
        bf16x8 af[4], bfr[4];
#pragma unroll
        for (int tm = 0; tm < 4; ++tm)
            af[tm] = as_frag(*(const int4*)(bufA + sw_off(tm * 16 + lrow, ko)));
#pragma unroll
        for (int g = 0; g < 4; ++g)
            bfr[g] = as_frag(*(const int4*)(wgp + (size_t)g * 16 * 256 + ko));
#pragma unroll
        for (int tm = 0; tm < 4; ++tm)
#pragma unroll
            for (int g = 0; g < 4; ++g)
                acc[tm][g] = __builtin_amdgcn_mfma_f32_16x16x32_bf16(af[tm], bfr[g], acc[tm][g], 0, 0, 0);
    }

    // epilogue: thread-local gate mixing for h = wv*16 + lrow
    {
        const int h = wv * 16 + lrow;
        const float b_r = bi[h] + bh[h];
        const float b_z = bi[128 + h] + bh[128 + h];
        const float b_n = bi[256 + h];
        const float b_h = bh[256 + h];
#pragma unroll
        for (int tm = 0; tm < 4; ++tm) {
#pragma unroll
            for (int r = 0; r < 4; ++r) {
                const int node = n0 + tm * 16 + lq * 4 + r;
                const float irhr = acc[tm][0][r] + b_r;
                const float izhz = acc[tm][1][r] + b_z;
                const float inn  = acc[tm][2][r] + b_n;
                const float hn   = acc[tm][3][r] + b_h;
                const float rg = 1.f / (1.f + expf(-irhr));
                const float zg = 1.f / (1.f + expf(-izhz));
                const float ng = tanhf(inn + rg * hn);
                const float xo = x[(size_t)node * H + h];
                x[(size_t)node * H + h] = (1.f - zg) * ng + zg * xo;
                aggr[(size_t)node * H + h] = 0.f;   // re-zero for next step
            }
        }
    }
}

// ---------------------------------------------------------------- decoder via MFMA (64 masked ids / block)
__global__ __launch_bounds__(256, 4) void dec_mfma(
        const float* __restrict__ x,
        const unsigned short* __restrict__ W1T, const float* __restrict__ b1,
        const unsigned short* __restrict__ W2T, const float* __restrict__ b2,
        const float* __restrict__ W3, const float* __restrict__ b3,
        float* __restrict__ out) {
    __shared__ unsigned short buf[64 * 256];   // 32 KB
    const int t = threadIdx.x;
    const int id0 = blockIdx.x * 64;
    const int wv = t >> 6, ln = t & 63, lrow = ln & 15, lq = ln >> 4;
    const int nbase = wv * 64;

    // stage bf16(x) for 64 masked ids into buf[:, 0:128]
    {
        const int m = t >> 2, q = t & 3;
        const int id = id0 + m;
        const int node = (id >> 3) * NND + (id & 7);
        const float* src = x + (size_t)node * H + q * 32;
#pragma unroll
        for (int i = 0; i < 8; ++i) {
            float4 v = *(const float4*)(src + i * 4);
            uint2 o; o.x = pkbf(v.x, v.y); o.y = pkbf(v.z, v.w);
            *(uint2*)(buf + sw_off(m, q * 32 + i * 4)) = o;
        }
    }
    __syncthreads();

    const f32x4 zero = {0.f, 0.f, 0.f, 0.f};

    // ---- layer 1: K=128 -> 256 cols
    {
        f32x4 acc[4][4];
#pragma unroll
        for (int i = 0; i < 4; ++i)
#pragma unroll
            for (int j = 0; j < 4; ++j) acc[i][j] = zero;
#pragma unroll
        for (int kq = 0; kq < 4; ++kq) {
            const int ko = kq * 32 + lq * 8;
            bf16x8 af[4], bfr[4];
#pragma unroll
            for (int tm = 0; tm < 4; ++tm)
                af[tm] = as_frag(*(const int4*)(buf + sw_off(tm * 16 + lrow, ko)));
#pragma unroll
            for (int tn = 0; tn < 4; ++tn)
                bfr[tn] = as_frag(*(const int4*)(W1T + (size_t)(nbase + tn * 16 + lrow) * 128 + ko));
#pragma unroll
            for (int tm = 0; tm < 4; ++tm)
#pragma unroll
                for (int tn = 0; tn < 4; ++tn)
                    acc[tm][tn] = __builtin_amdgcn_mfma_f32_16x16x32_bf16(af[tm], bfr[tn], acc[tm][tn], 0, 0, 0);
        }
        __syncthreads();
#pragma unroll
        for (int tn = 0; tn < 4; ++tn) {
            const int n = nbase + tn * 16 + lrow;
            const float bias = b1[n];
#pragma unroll
            for (int tm = 0; tm < 4; ++tm)
#pragma unroll
                for (int r = 0; r < 4; ++r) {
                    const int m = tm * 16 + lq * 4 + r;
                    buf[sw_off(m, n)] = f2bf(fast_tanh(acc[tm][tn][r] + bias));
                }
        }
    }
    __syncthreads();

    // ---- layer 2: K=256 -> 256 cols
    {
        f32x4 acc[4][4];
#pragma unroll
        for (int i = 0; i < 4; ++i)
#pragma unroll
            for (int j = 0; j < 4; ++j) acc[i][j] = zero;
#pragma unroll
        for (int kq = 0; kq < 8; ++kq) {
            const int ko = kq * 32 + lq * 8;
            bf16x8 af[4], bfr[4];
#pragma unroll
            for (int tm = 0; tm < 4; ++tm)
                af[tm] = as_frag(*(const int4*)(buf + sw_off(tm * 16 + lrow, ko)));
#pragma unroll
            for (int tn = 0; tn < 4; ++tn)
                bfr[tn] = as_frag(*(const int4*)(W2T + (size_t)(nbase + tn * 16 + lrow) * 256 + ko));
#pragma unroll
            for (int tm = 0; tm < 4; ++tm)
#pragma unroll
                for (int tn = 0; tn < 4; ++tn)
                    acc[tm][tn] = __builtin_amdgcn_mfma_f32_16x16x32_bf16(af[tm], bfr[tn], acc[tm][tn], 0, 0, 0);
        }
        __syncthreads();
#pragma unroll
        for (int tn = 0; tn < 4; ++tn) {
            const int n = nbase + tn * 16 + lrow;
            const float bias = b2[n];
#pragma unroll
            for (int tm = 0; tm < 4; ++tm)
#pragma unroll
                for (int r = 0; r < 4; ++r) {
                    const int m = tm * 16 + lq * 4 + r;
                    buf[sw_off(m, n)] = f2bf(fast_tanh(acc[tm][tn][r] + bias));
                }
        }
    }
    __syncthreads();

    // ---- layer 3: 256 -> 1, 4 threads per id, shuffle reduce
    {
        const int m = t >> 2, p = t & 3;
        float s = 0.f;
#pragma unroll
        for (int i = 0; i < 64; ++i) {
            const int k = p * 64 + i;
            const float a = __uint_as_float((unsigned int)buf[sw_off(m, k)] << 16);
            s += a * W3[k];
        }
        s += __shfl_xor(s, 1);
        s += __shfl_xor(s, 2);
        if (p == 0) out[id0 + m] = s + b3[0];
    }
}

// ---------------------------------------------------------------- launch
extern "C" void kernel_launch(void* const* d_in, const int* in_sizes, int n_in,
                              void* d_out, int out_size, void* d_ws, size_t ws_size,
                              hipStream_t stream) {
    const float* obs    = (const float*)d_in[0];
    const int*   edges  = (const int*)  d_in[1];
    const float* enc_W  = (const float*)d_in[2];
    const float* enc_b  = (const float*)d_in[3];
    const float* msg_W1 = (const float*)d_in[4];
    const float* msg_b1 = (const float*)d_in[5];
    const float* msg_W2 = (const float*)d_in[6];
    const float* msg_b2 = (const float*)d_in[7];
    const float* msg_W3 = (const float*)d_in[8];
    const float* msg_b3 = (const float*)d_in[9];
    const float* gru_Wi = (const float*)d_in[10];
    const float* gru_Wh = (const float*)d_in[11];
    const float* gru_bi = (const float*)d_in[12];
    const float* gru_bh = (const float*)d_in[13];
    const float* dec_W1 = (const float*)d_in[14];
    const float* dec_b1 = (const float*)d_in[15];
    const float* dec_W2 = (const float*)d_in[16];
    const float* dec_b2 = (const float*)d_in[17];
    const float* dec_W3 = (const float*)d_in[18];
    const float* dec_b3 = (const float*)d_in[19];

    float* x       = (float*)d_ws;                 // BN*128
    float* aggr    = x + (size_t)BN * H;           // BN*128
    float* inv_deg = aggr + (size_t)BN * H;        // BN
    unsigned short* wbf = (unsigned short*)(inv_deg + BN);   // 1277952 bf16

    hipMemsetAsync(aggr, 0, (size_t)BN * H * sizeof(float), stream);
    deg_kernel<<<(BGR + 255) / 256, 256, 0, stream>>>(edges, inv_deg);
    wt_kernel<<<1277952 / 256, 256, 0, stream>>>(msg_W1, msg_W2, msg_W3, gru_Wi, gru_Wh,
                                                 dec_W1, dec_W2, wbf);
    enc_kernel<<<BN * H / 256, 256, 0, stream>>>(obs, enc_W, enc_b, x);

    for (int s = 0; s < 4; ++s) {
        const unsigned short* W1T = wbf + (size_t)s * 65536;
        const unsigned short* W2T = wbf + 262144 + (size_t)s * 65536;
        const unsigned short* W3T = wbf + 524288 + (size_t)s * 32768;
        const unsigned short* WGs = wbf + 655360 + (size_t)s * 131072;
        msg_mfma<<<ETOT / 64, 512, 0, stream>>>(
            x, edges,
            W1T, msg_b1 + (size_t)s * 256,
            W2T, msg_b2 + (size_t)s * 256,
            W3T,
            aggr);
        gru_mfma<<<BN / 64, 512, 0, stream>>>(
            x, aggr, inv_deg, WGs, msg_b3 + (size_t)s * 128,
            gru_bi + (size_t)s * 384, gru_bh + (size_t)s * 384);
    }

    dec_mfma<<<BGR * 8 / 64, 256, 0, stream>>>(
        x, wbf + 1179648, dec_b1, wbf + 1212416, dec_b2, dec_W3, dec_b3, (float*)d_out);
}

// Round 8
// 1340.249 us; speedup vs baseline: 1.1063x; 1.1063x over previous
//
#include <hip/hip_runtime.h>
#include <hip/hip_bf16.h>
#include <math.h>

#define BGR   8192        // graphs
#define NND   9           // nodes per graph
#define BN    73728       // BGR*NND
#define NE    131072      // BGR*16 explicit edges
#define ETOT  204800      // NE + BN (self loops)
#define H     128
#define MH    256
#define FIN   15

typedef __bf16 bf16_t;
typedef bf16_t bf16x8 __attribute__((ext_vector_type(8)));
typedef float  f32x4  __attribute__((ext_vector_type(4)));
typedef float  f32x16 __attribute__((ext_vector_type(16)));

__device__ __forceinline__ unsigned short f2bf(float f) {
    unsigned int u = __float_as_uint(f);
    u += 0x7fff + ((u >> 16) & 1);           // RNE (inputs are finite)
    return (unsigned short)(u >> 16);
}
__device__ __forceinline__ unsigned int pkbf(float a, float b) {
    union { __hip_bfloat162 h; unsigned int u; } un;
    un.h = __float22bfloat162_rn(make_float2(a, b));
    return un.u;
}
__device__ __forceinline__ bf16x8 as_frag(int4 v) {
    union { int4 i; bf16x8 f; } u; u.i = v; return u.f;
}
__device__ __forceinline__ float fast_tanh(float v) {
    float e = __expf(2.0f * v);
    return 1.0f - __fdividef(2.0f, e + 1.0f);
}
// 16-deep XOR swizzle for 32-row MFMA fragments (2 lanes/bank = free)
__device__ __forceinline__ int sw16(int m, int k) {
    return m * 256 + ((((k >> 3) ^ (m & 15)) << 3) | (k & 7));
}
// legacy 8-deep swizzle (16x16 kernels: gru, dec)
__device__ __forceinline__ int sw_off(int m, int k) {
    return m * 256 + ((((k >> 3) ^ (m & 7)) << 3) | (k & 7));
}

// ---------------------------------------------------------------- deg kernel
__global__ void deg_kernel(const int* __restrict__ edges, float* __restrict__ inv_deg) {
    int g = blockIdx.x * 256 + threadIdx.x;
    if (g >= BGR) return;
    int cnt[NND];
#pragma unroll
    for (int n = 0; n < NND; ++n) cnt[n] = 1;   // self loop
    for (int j = 0; j < 16; ++j) {
        int d = edges[g * 32 + 16 + j];
#pragma unroll
        for (int n = 0; n < NND; ++n) cnt[n] += (d == n) ? 1 : 0;
    }
#pragma unroll
    for (int n = 0; n < NND; ++n) inv_deg[g * NND + n] = 1.0f / (float)cnt[n];
}

// ---------------------------------------------------------------- encoder
__global__ void enc_kernel(const float* __restrict__ obs, const float* __restrict__ W,
                           const float* __restrict__ b, float* __restrict__ x) {
    int tid = blockIdx.x * 256 + threadIdx.x;     // BN*128 threads
    int i = tid >> 7, h = tid & 127;
    float acc = b[h];
#pragma unroll
    for (int k = 0; k < FIN; ++k) acc += obs[i * FIN + k] * W[k * H + h];
    x[i * H + h] = tanhf(acc);
}

// ---------------------------------------------------------------- weight transpose+bf16
// out: [W1T 4x256x256][W2T 4x256x256][W3T 4x128x256][WG 4x512x256][dW1T 256x128][dW2T 256x256]
// WG packed col p = w*64 + gate*16 + c  ->  (gate, h = w*16 + c), w=0..7
__global__ void wt_kernel(const float* __restrict__ W1, const float* __restrict__ W2,
                          const float* __restrict__ W3, const float* __restrict__ Wi,
                          const float* __restrict__ Wh, const float* __restrict__ dW1,
                          const float* __restrict__ dW2, unsigned short* __restrict__ out) {
    int idx = blockIdx.x * 256 + threadIdx.x;     // 1277952 total
    float v;
    if (idx < 262144) {
        int s = idx >> 16, r = idx & 65535, n = r >> 8, k = r & 255;
        v = W1[(s << 16) + (k << 8) + n];
    } else if (idx < 524288) {
        int i2 = idx - 262144;
        int s = i2 >> 16, r = i2 & 65535, n = r >> 8, k = r & 255;
        v = W2[(s << 16) + (k << 8) + n];
    } else if (idx < 655360) {
        int i3 = idx - 524288;
        int s = i3 >> 15, r = i3 & 32767, n = r >> 8, k = r & 255;
        v = W3[(s << 15) + (k << 7) + n];
    } else if (idx < 1179648) {
        int i4 = idx - 655360;                    // 0..524287
        int s = i4 >> 17, rr = i4 & 131071;
        int p = rr >> 8, k = rr & 255;
        int w = p >> 6, rem = p & 63;
        int gate = rem >> 4, c = rem & 15;
        int h = w * 16 + c;
        const int sb = s * 49152;                 // 128*384
        if (gate == 0)      v = (k < 128) ? Wi[sb + k * 384 + h]       : Wh[sb + (k - 128) * 384 + h];
        else if (gate == 1) v = (k < 128) ? Wi[sb + k * 384 + 128 + h] : Wh[sb + (k - 128) * 384 + 128 + h];
        else if (gate == 2) v = (k < 128) ? Wi[sb + k * 384 + 256 + h] : 0.f;
        else                v = (k < 128) ? 0.f                        : Wh[sb + (k - 128) * 384 + 256 + h];
    } else if (idx < 1212416) {
        int i5 = idx - 1179648;                   // dW1T [256][128]
        int n = i5 >> 7, k = i5 & 127;
        v = dW1[k * 256 + n];
    } else {
        int i6 = idx - 1212416;                   // dW2T [256][256]
        int n = i6 >> 8, k = i6 & 255;
        v = dW2[k * 256 + n];
    }
    out[idx] = f2bf(v);
}

// ---------------------------------------------------------------- fused msg MLP, 32x32x16 MFMA bf16
// 64 edges / block, 512 threads (8 waves). Layers 1-2: wave w owns n-tile w*32 (no W
// redundancy), both 32-row m-tiles. Layer 3: wave = (m-tile wv&1, n-tile wv>>1).
// Double-buffered LDS (A/B) -> only 3 barriers. C-layout: col=lane&31,
// row=(reg&3)+8*(reg>>2)+4*(lane>>5) [HW-verified m74/m101].
__global__ __launch_bounds__(512, 4) void msg_mfma(
        const float* __restrict__ x, const int* __restrict__ edges,
        const unsigned short* __restrict__ W1T, const float* __restrict__ b1,
        const unsigned short* __restrict__ W2T, const float* __restrict__ b2,
        const unsigned short* __restrict__ W3T,
        float* __restrict__ aggr) {
    __shared__ unsigned short bufA[64 * 256];   // 32 KB
    __shared__ unsigned short bufB[64 * 256];   // 32 KB
    __shared__ int sdst[64];
    const int t  = threadIdx.x;
    const int e0 = blockIdx.x * 64;
    const int wv = t >> 6;        // 0..7
    const int ln = t & 63;
    const int l31 = ln & 31;
    const int lh  = ln >> 5;      // k-half selector

    // ---- stage A0 = bf16(concat(x[dst], x[src])) into bufA; also dst indices
    if (t < 64) {
        const int eg = e0 + t;
        sdst[t] = (eg < NE) ? ((eg >> 4) * NND + edges[(eg >> 4) * 32 + 16 + (eg & 15)])
                            : (eg - NE);
    }
    {
        const int row  = t >> 2;          // 0..127
        const int q    = t & 3;
        const int e    = row & 63;
        const int side = row >> 6;        // 0 -> dst cols 0..127, 1 -> src cols 128..255
        const int eg   = e0 + e;
        int node;
        if (eg < NE) {
            int g = eg >> 4, j = eg & 15;
            node = g * NND + (side ? edges[g * 32 + j] : edges[g * 32 + 16 + j]);
        } else {
            node = eg - NE;
        }
        const float* xs = x + (size_t)node * H + q * 32;
        const int kbase = side * 128 + q * 32;
#pragma unroll
        for (int i = 0; i < 8; ++i) {
            float4 v = *(const float4*)(xs + i * 4);
            uint2 o;
            o.x = pkbf(v.x, v.y); o.y = pkbf(v.z, v.w);
            *(uint2*)(bufA + sw16(e, kbase + i * 4)) = o;
        }
    }
    __syncthreads();   // barrier 1

    // ---- layer 1: read bufA, write bufB
    {
        f32x16 acc0, acc1;
#pragma unroll
        for (int i = 0; i < 16; ++i) { acc0[i] = 0.f; acc1[i] = 0.f; }
        const unsigned short* wp = W1T + (size_t)(wv * 32 + l31) * 256 + lh * 8;
#pragma unroll
        for (int ks = 0; ks < 16; ++ks) {
            const int kk = ks * 16 + lh * 8;
            bf16x8 a0 = as_frag(*(const int4*)(bufA + sw16(l31, kk)));
            bf16x8 a1 = as_frag(*(const int4*)(bufA + sw16(32 + l31, kk)));
            bf16x8 bw = as_frag(*(const int4*)(wp + ks * 16));
            acc0 = __builtin_amdgcn_mfma_f32_32x32x16_bf16(a0, bw, acc0, 0, 0, 0);
            acc1 = __builtin_amdgcn_mfma_f32_32x32x16_bf16(a1, bw, acc1, 0, 0, 0);
        }
        const int n = wv * 32 + l31;
        const float bias = b1[n];
#pragma unroll
        for (int reg = 0; reg < 16; ++reg) {
            const int mrow = (reg & 3) + ((reg >> 2) << 3) + (lh << 2);
            bufB[sw16(mrow, n)]      = f2bf(fast_tanh(acc0[reg] + bias));
            bufB[sw16(32 + mrow, n)] = f2bf(fast_tanh(acc1[reg] + bias));
        }
    }
    __syncthreads();   // barrier 2

    // ---- layer 2: read bufB, write bufA
    {
        f32x16 acc0, acc1;
#pragma unroll
        for (int i = 0; i < 16; ++i) { acc0[i] = 0.f; acc1[i] = 0.f; }
        const unsigned short* wp = W2T + (size_t)(wv * 32 + l31) * 256 + lh * 8;
#pragma unroll
        for (int ks = 0; ks < 16; ++ks) {
            const int kk = ks * 16 + lh * 8;
            bf16x8 a0 = as_frag(*(const int4*)(bufB + sw16(l31, kk)));
            bf16x8 a1 = as_frag(*(const int4*)(bufB + sw16(32 + l31, kk)));
            bf16x8 bw = as_frag(*(const int4*)(wp + ks * 16));
            acc0 = __builtin_amdgcn_mfma_f32_32x32x16_bf16(a0, bw, acc0, 0, 0, 0);
            acc1 = __builtin_amdgcn_mfma_f32_32x32x16_bf16(a1, bw, acc1, 0, 0, 0);
        }
        const int n = wv * 32 + l31;
        const float bias = b2[n];
#pragma unroll
        for (int reg = 0; reg < 16; ++reg) {
            const int mrow = (reg & 3) + ((reg >> 2) << 3) + (lh << 2);
            bufA[sw16(mrow, n)]      = f2bf(fast_tanh(acc0[reg] + bias));
            bufA[sw16(32 + mrow, n)] = f2bf(fast_tanh(acc1[reg] + bias));
        }
    }
    __syncthreads();   // barrier 3

    // ---- layer 3: read bufA; N=128; wave (mt = wv&1, nq = wv>>1); atomic scatter
    {
        const int mt = wv & 1, nq = wv >> 1;
        const int n = nq * 32 + l31;
        f32x16 acc;
#pragma unroll
        for (int i = 0; i < 16; ++i) acc[i] = 0.f;
        const unsigned short* wp = W3T + (size_t)n * 256 + lh * 8;
#pragma unroll
        for (int ks = 0; ks < 16; ++ks) {
            const int kk = ks * 16 + lh * 8;
            bf16x8 a = as_frag(*(const int4*)(bufA + sw16(mt * 32 + l31, kk)));
            bf16x8 bw = as_frag(*(const int4*)(wp + ks * 16));
            acc = __builtin_amdgcn_mfma_f32_32x32x16_bf16(a, bw, acc, 0, 0, 0);
        }
#pragma unroll
        for (int reg = 0; reg < 16; ++reg) {
            const int m = mt * 32 + (reg & 3) + ((reg >> 2) << 3) + (lh << 2);
            atomicAdd(aggr + (size_t)sdst[m] * H + n, acc[reg]);
        }
    }
}

// ---------------------------------------------------------------- GRU via MFMA (64 nodes / block, 512 thr)
// Wave w owns packed cols w*64..w*64+63 = all 4 gates of h-slice w*16..w*16+15.
__global__ __launch_bounds__(512, 4) void gru_mfma(
        float* __restrict__ x, float* __restrict__ aggr, const float* __restrict__ inv_deg,
        const unsigned short* __restrict__ WG, const float* __restrict__ b3m,
        const float* __restrict__ bi, const float* __restrict__ bh) {
    __shared__ unsigned short bufA[64 * 256];   // 32 KB
    const int t = threadIdx.x;
    const int n0 = blockIdx.x * 64;
    const int wv = t >> 6, ln = t & 63, lrow = ln & 15, lq = ln >> 4;

    // stage A = bf16([aggr*inv_deg + b3 | x]): m = t>>3, k-slice q*32
    {
        const int m = t >> 3;
        const int q = t & 7;
        const int k0 = q * 32;
        const int node = n0 + m;
        if (q < 4) {
            const float scale = inv_deg[node];
            const float* src = aggr + (size_t)node * H + k0;
#pragma unroll
            for (int i = 0; i < 8; ++i) {
                float4 v = *(const float4*)(src + i * 4);
                const float4 bb = *(const float4*)(b3m + k0 + i * 4);
                v.x = v.x * scale + bb.x; v.y = v.y * scale + bb.y;
                v.z = v.z * scale + bb.z; v.w = v.w * scale + bb.w;
                uint2 o; o.x = pkbf(v.x, v.y); o.y = pkbf(v.z, v.w);
                *(uint2*)(bufA + sw_off(m, k0 + i * 4)) = o;
            }
        } else {
            const float* src = x + (size_t)node * H + (k0 - 128);
#pragma unroll
            for (int i = 0; i < 8; ++i) {
                float4 v = *(const float4*)(src + i * 4);
                uint2 o; o.x = pkbf(v.x, v.y); o.y = pkbf(v.z, v.w);
                *(uint2*)(bufA + sw_off(m, k0 + i * 4)) = o;
            }
        }
    }
    __syncthreads();

    const f32x4 zero = {0.f, 0.f, 0.f, 0.f};
    f32x4 acc[4][4];    // [m-tile][gate]
#pragma unroll
    for (int i = 0; i < 4; ++i)
#pragma unroll
        for (int j = 0; j < 4; ++j) acc[i][j] = zero;

    const unsigned short* wgp = WG + (size_t)(wv * 64 + lrow) * 256;
#pragma unroll
    for (int kq = 0; kq < 8; ++kq) {
        const int ko = kq * 32 + lq * 8;
        bf16x8 af[4], bfr[4];
#pragma unroll
        for (int tm = 0; tm < 4; ++tm)
            af[tm] = as_frag(*(const int4*)(bufA + sw_off(tm * 16 + lrow, ko)));
#pragma unroll
        for (int g = 0; g < 4; ++g)
            bfr[g] = as_frag(*(const int4*)(wgp + (size_t)g * 16 * 256 + ko));
#pragma unroll
        for (int tm = 0; tm < 4; ++tm)
#pragma unroll
            for (int g = 0; g < 4; ++g)
                acc[tm][g] = __builtin_amdgcn_mfma_f32_16x16x32_bf16(af[tm], bfr[g], acc[tm][g], 0, 0, 0);
    }

    // epilogue: thread-local gate mixing for h = wv*16 + lrow
    {
        const int h = wv * 16 + lrow;
        const float b_r = bi[h] + bh[h];
        const float b_z = bi[128 + h] + bh[128 + h];
        const float b_n = bi[256 + h];
        const float b_h = bh[256 + h];
#pragma unroll
        for (int tm = 0; tm < 4; ++tm) {
#pragma unroll
            for (int r = 0; r < 4; ++r) {
                const int node = n0 + tm * 16 + lq * 4 + r;
                const float irhr = acc[tm][0][r] + b_r;
                const float izhz = acc[tm][1][r] + b_z;
                const float inn  = acc[tm][2][r] + b_n;
                const float hn   = acc[tm][3][r] + b_h;
                const float rg = 1.f / (1.f + expf(-irhr));
                const float zg = 1.f / (1.f + expf(-izhz));
                const float ng = tanhf(inn + rg * hn);
                const float xo = x[(size_t)node * H + h];
                x[(size_t)node * H + h] = (1.f - zg) * ng + zg * xo;
                aggr[(size_t)node * H + h] = 0.f;   // re-zero for next step
            }
        }
    }
}

// ---------------------------------------------------------------- decoder via MFMA (64 masked ids / block)
__global__ __launch_bounds__(256, 4) void dec_mfma(
        const float* __restrict__ x,
        const unsigned short* __restrict__ W1T, const float* __restrict__ b1,
        const unsigned short* __restrict__ W2T, const float* __restrict__ b2,
        const float* __restrict__ W3, const float* __restrict__ b3,
        float* __restrict__ out) {
    __shared__ unsigned short buf[64 * 256];   // 32 KB
    const int t = threadIdx.x;
    const int id0 = blockIdx.x * 64;
    const int wv = t >> 6, ln = t & 63, lrow = ln & 15, lq = ln >> 4;
    const int nbase = wv * 64;

    // stage bf16(x) for 64 masked ids into buf[:, 0:128]
    {
        const int m = t >> 2, q = t & 3;
        const int id = id0 + m;
        const int node = (id >> 3) * NND + (id & 7);
        const float* src = x + (size_t)node * H + q * 32;
#pragma unroll
        for (int i = 0; i < 8; ++i) {
            float4 v = *(const float4*)(src + i * 4);
            uint2 o; o.x = pkbf(v.x, v.y); o.y = pkbf(v.z, v.w);
            *(uint2*)(buf + sw_off(m, q * 32 + i * 4)) = o;
        }
    }
    __syncthreads();

    const f32x4 zero = {0.f, 0.f, 0.f, 0.f};

    // ---- layer 1: K=128 -> 256 cols
    {
        f32x4 acc[4][4];
#pragma unroll
        for (int i = 0; i < 4; ++i)
#pragma unroll
            for (int j = 0; j < 4; ++j) acc[i][j] = zero;
#pragma unroll
        for (int kq = 0; kq < 4; ++kq) {
            const int ko = kq * 32 + lq * 8;
            bf16x8 af[4], bfr[4];
#pragma unroll
            for (int tm = 0; tm < 4; ++tm)
                af[tm] = as_frag(*(const int4*)(buf + sw_off(tm * 16 + lrow, ko)));
#pragma unroll
            for (int tn = 0; tn < 4; ++tn)
                bfr[tn] = as_frag(*(const int4*)(W1T + (size_t)(nbase + tn * 16 + lrow) * 128 + ko));
#pragma unroll
            for (int tm = 0; tm < 4; ++tm)
#pragma unroll
                for (int tn = 0; tn < 4; ++tn)
                    acc[tm][tn] = __builtin_amdgcn_mfma_f32_16x16x32_bf16(af[tm], bfr[tn], acc[tm][tn], 0, 0, 0);
        }
        __syncthreads();
#pragma unroll
        for (int tn = 0; tn < 4; ++tn) {
            const int n = nbase + tn * 16 + lrow;
            const float bias = b1[n];
#pragma unroll
            for (int tm = 0; tm < 4; ++tm)
#pragma unroll
                for (int r = 0; r < 4; ++r) {
                    const int m = tm * 16 + lq * 4 + r;
                    buf[sw_off(m, n)] = f2bf(fast_tanh(acc[tm][tn][r] + bias));
                }
        }
    }
    __syncthreads();

    // ---- layer 2: K=256 -> 256 cols
    {
        f32x4 acc[4][4];
#pragma unroll
        for (int i = 0; i < 4; ++i)
#pragma unroll
            for (int j = 0; j < 4; ++j) acc[i][j] = zero;
#pragma unroll
        for (int kq = 0; kq < 8; ++kq) {
            const int ko = kq * 32 + lq * 8;
            bf16x8 af[4], bfr[4];
#pragma unroll
            for (int tm = 0; tm < 4; ++tm)
                af[tm] = as_frag(*(const int4*)(buf + sw_off(tm * 16 + lrow, ko)));
#pragma unroll
            for (int tn = 0; tn < 4; ++tn)
                bfr[tn] = as_frag(*(const int4*)(W2T + (size_t)(nbase + tn * 16 + lrow) * 256 + ko));
#pragma unroll
            for (int tm = 0; tm < 4; ++tm)
#pragma unroll
                for (int tn = 0; tn < 4; ++tn)
                    acc[tm][tn] = __builtin_amdgcn_mfma_f32_16x16x32_bf16(af[tm], bfr[tn], acc[tm][tn], 0, 0, 0);
        }
        __syncthreads();
#pragma unroll
        for (int tn = 0; tn < 4; ++tn) {
            const int n = nbase + tn * 16 + lrow;
            const float bias = b2[n];
#pragma unroll
            for (int tm = 0; tm < 4; ++tm)
#pragma unroll
                for (int r = 0; r < 4; ++r) {
                    const int m = tm * 16 + lq * 4 + r;
                    buf[sw_off(m, n)] = f2bf(fast_tanh(acc[tm][tn][r] + bias));
                }
        }
    }
    __syncthreads();

    // ---- layer 3: 256 -> 1, 4 threads per id, shuffle reduce
    {
        const int m = t >> 2, p = t & 3;
        float s = 0.f;
#pragma unroll
        for (int i = 0; i < 64; ++i) {
            const int k = p * 64 + i;
            const float a = __uint_as_float((unsigned int)buf[sw_off(m, k)] << 16);
            s += a * W3[k];
        }
        s += __shfl_xor(s, 1);
        s += __shfl_xor(s, 2);
        if (p == 0) out[id0 + m] = s + b3[0];
    }
}

// ---------------------------------------------------------------- launch
extern "C" void kernel_launch(void* const* d_in, const int* in_sizes, int n_in,
                              void* d_out, int out_size, void* d_ws, size_t ws_size,
                              hipStream_t stream) {
    const float* obs    = (const float*)d_in[0];
    const int*   edges  = (const int*)  d_in[1];
    const float* enc_W  = (const float*)d_in[2];
    const float* enc_b  = (const float*)d_in[3];
    const float* msg_W1 = (const float*)d_in[4];
    const float* msg_b1 = (const float*)d_in[5];
    const float* msg_W2 = (const float*)d_in[6];
    const float* msg_b2 = (const float*)d_in[7];
    const float* msg_W3 = (const float*)d_in[8];
    const float* msg_b3 = (const float*)d_in[9];
    const float* gru_Wi = (const float*)d_in[10];
    const float* gru_Wh = (const float*)d_in[11];
    const float* gru_bi = (const float*)d_in[12];
    const float* gru_bh = (const float*)d_in[13];
    const float* dec_W1 = (const float*)d_in[14];
    const float* dec_b1 = (const float*)d_in[15];
    const float* dec_W2 = (const float*)d_in[16];
    const float* dec_b2 = (const float*)d_in[17];
    const float* dec_W3 = (const float*)d_in[18];
    const float* dec_b3 = (const float*)d_in[19];

    float* x       = (float*)d_ws;                 // BN*128
    float* aggr    = x + (size_t)BN * H;           // BN*128
    float* inv_deg = aggr + (size_t)BN * H;        // BN
    unsigned short* wbf = (unsigned short*)(inv_deg + BN);   // 1277952 bf16

    hipMemsetAsync(aggr, 0, (size_t)BN * H * sizeof(float), stream);
    deg_kernel<<<(BGR + 255) / 256, 256, 0, stream>>>(edges, inv_deg);
    wt_kernel<<<1277952 / 256, 256, 0, stream>>>(msg_W1, msg_W2, msg_W3, gru_Wi, gru_Wh,
                                                 dec_W1, dec_W2, wbf);
    enc_kernel<<<BN * H / 256, 256, 0, stream>>>(obs, enc_W, enc_b, x);

    for (int s = 0; s < 4; ++s) {
        const unsigned short* W1T = wbf + (size_t)s * 65536;
        const unsigned short* W2T = wbf + 262144 + (size_t)s * 65536;
        const unsigned short* W3T = wbf + 524288 + (size_t)s * 32768;
        const unsigned short* WGs = wbf + 655360 + (size_t)s * 131072;
        msg_mfma<<<ETOT / 64, 512, 0, stream>>>(
            x, edges,
            W1T, msg_b1 + (size_t)s * 256,
            W2T, msg_b2 + (size_t)s * 256,
            W3T,
            aggr);
        gru_mfma<<<BN / 64, 512, 0, stream>>>(
            x, aggr, inv_deg, WGs, msg_b3 + (size_t)s * 128,
            gru_bi + (size_t)s * 384, gru_bh + (size_t)s * 384);
    }

    dec_mfma<<<BGR * 8 / 64, 256, 0, stream>>>(
        x, wbf + 1179648, dec_b1, wbf + 1212416, dec_b2, dec_W3, dec_b3, (float*)d_out);
}